// Round 6
// baseline (735.809 us; speedup 1.0000x reference)
//
#include <hip/hip_runtime.h>
#include <hip/hip_bf16.h>
#include <stdint.h>

#define AS1 __attribute__((address_space(1)))
#define AS3 __attribute__((address_space(3)))

typedef __bf16 bf16x8_t __attribute__((ext_vector_type(8)));
typedef __bf16 bf16x4_t __attribute__((ext_vector_type(4)));
typedef float  f32x4_t  __attribute__((ext_vector_type(4)));

constexpr int MD = 8192;     // 4*2048 rows of x
constexpr int ND = 11008;    // weight rows = output cols
constexpr int KD = 4096;

// ---- 8-phase 256^2 kernel geometry ----
constexpr int BM8 = 256, BN8 = 256, BK8 = 64;
constexpr int MT8 = MD / BM8;      // 32
constexpr int NT8 = ND / BN8;      // 43
constexpr int NWG8 = MT8 * NT8;    // 1376 (%8==0 -> bijective XCD swizzle)

// ---- fallback 128^2 kernel geometry ----
constexpr int BM = 128, BN = 128, BK = 32;
constexpr int MT = MD / BM, NT = ND / BN, NWG = MT * NT;
constexpr int KSTEPS = KD / BK;

// ---------------- scale = mean(|W|) + eps (two-stage, deterministic, f64 acc) ----
__global__ void k_abs_partial(const float* __restrict__ w, double* __restrict__ part) {
  __shared__ double sm[256];
  const size_t n4 = (size_t)ND * KD / 4;
  const f32x4_t* w4 = (const f32x4_t*)w;
  double s = 0.0;
  for (size_t i = (size_t)blockIdx.x * 256 + threadIdx.x; i < n4; i += (size_t)gridDim.x * 256) {
    f32x4_t v = __builtin_nontemporal_load(&w4[i]);
    s += (double)fabsf(v[0]) + (double)fabsf(v[1]) + (double)fabsf(v[2]) + (double)fabsf(v[3]);
  }
  sm[threadIdx.x] = s;
  __syncthreads();
  for (int o = 128; o > 0; o >>= 1) {
    if ((int)threadIdx.x < o) sm[threadIdx.x] += sm[threadIdx.x + o];
    __syncthreads();
  }
  if (threadIdx.x == 0) part[blockIdx.x] = sm[0];
}

__global__ void k_abs_final(const double* __restrict__ part, float* __restrict__ scale_out) {
  __shared__ double sm[256];
  double s = 0.0;
  for (int i = threadIdx.x; i < 2048; i += 256) s += part[i];
  sm[threadIdx.x] = s;
  __syncthreads();
  for (int o = 128; o > 0; o >>= 1) {
    if ((int)threadIdx.x < o) sm[threadIdx.x] += sm[threadIdx.x + o];
    __syncthreads();
  }
  if (threadIdx.x == 0) {
    double mean = sm[0] / (double)((size_t)ND * KD);
    scale_out[0] = (float)mean + 1e-5f;
  }
}

// ---------------- prepass: ternary-quantize W -> bf16 {-1,0,1} -------------------
__global__ void k_quant_w(const float* __restrict__ w, const float* __restrict__ scale_p,
                          __bf16* __restrict__ wq) {
  const float s = scale_p[0];
  const size_t n4 = (size_t)ND * KD / 4;
  const f32x4_t* w4 = (const f32x4_t*)w;
  bf16x4_t* q4 = (bf16x4_t*)wq;
  for (size_t i = (size_t)blockIdx.x * 256 + threadIdx.x; i < n4; i += (size_t)gridDim.x * 256) {
    f32x4_t v = __builtin_nontemporal_load(&w4[i]);   // w is dead after this pass
    bf16x4_t h;
#pragma unroll
    for (int j = 0; j < 4; ++j) {
      float q = rintf(v[j] / s);
      q = fminf(1.f, fmaxf(-1.f, q));
      h[j] = (__bf16)q;
    }
    q4[i] = h;   // wq stays cacheable: GEMM reads it next
  }
}

// ---------------- prepass: x fp32 -> bf16 ---------------------------------------
__global__ void k_conv_x(const float* __restrict__ x, __bf16* __restrict__ xb) {
  const size_t n4 = (size_t)MD * KD / 4;
  const f32x4_t* x4 = (const f32x4_t*)x;
  bf16x4_t* o4 = (bf16x4_t*)xb;
  for (size_t i = (size_t)blockIdx.x * 256 + threadIdx.x; i < n4; i += (size_t)gridDim.x * 256) {
    f32x4_t v = __builtin_nontemporal_load(&x4[i]);   // x is dead after this pass
    bf16x4_t h;
#pragma unroll
    for (int j = 0; j < 4; ++j) h[j] = (__bf16)v[j];
    o4[i] = h;   // xb stays cacheable
  }
}

// ================= 8-phase 256x256 GEMM (m201-style template) ====================
// C[M,N] = Xb[M,K] * Wq[N,K]^T * scale. 512 thr = 8 waves (2M x 4N), each wave
// owns 128x64 output. BK=64, 2 K-tiles/iteration, 8 phases. LDS 128 KiB.
// XOR slot-swizzle applied on BOTH sides (rule #21).
//
// ROUND 6 CHANGE: earliest-legal stage ring + vmcnt(6) (3 half-tiles in flight,
// the template's canonical depth). Buffer-liveness: buf0.A read P1,P3; buf0.B
// read P1,P2; buf1.A read P5,P7; buf1.B read P5,P6 (both M-halves read
// simultaneously by different waves, so liveness is per (buf,op)). Stages are
// placed right after the owning buffer's last read (barrier-separated, so
// race-free; async LDS writes cannot land before issue):
//   P1: rd A0.mh0-3+B0.n0-1 (12) | stage b1.A.h1 <- T1          | lgkm8
//   P2: rd B0.n2-3 (4)           | -
//   P3: rd A0.mh4-7 (8)          | stage b0.B.h0 <- T2
//   P4: -                        | stage b0.B.h1, b0.A.h0 <- T2 | VMC(6)
//   P5: rd A1.mh0-3+B1.n0-1 (12) | stage b0.A.h1 <- T2          | lgkm8
//   P6: rd B1.n2-3 (4)           | -
//   P7: rd A1.mh4-7 (8)          | stage b1.B.h0 <- T3
//   P8: -                        | stage b1.B.h1, b1.A.h0 <- T3 | VMC(6)
// In-order vmcnt ledger (loads/phase: 2,0,2,4,2,0,2,4):
//   VMC(6)@P4: outstanding <= prevP7(2)+prevP8(4)+P1(2)+P3(2)+P4(4)=14; oldest 8
//     = prevP7+prevP8+P1 = ALL of buf1 T1's staging -> landed before P5 reads.
//   VMC(6)@P8: outstanding <= P3..P8 = 14; oldest 8 = P3+P4+P5 = ALL of buf0 T2
//     -> landed before next-P1 reads. Min stage->use distance: 4 phases.

#define BAR8()   __builtin_amdgcn_s_barrier()
#define LGKM0()  asm volatile("s_waitcnt lgkmcnt(0)")
#define LGKM8()  asm volatile("s_waitcnt lgkmcnt(8)")
#define VMC(N)   asm volatile("s_waitcnt vmcnt(" #N ")" ::: "memory")

#define RD_A(BUF, MOFF)                                                          \
  _Pragma("unroll") for (int mm = 0; mm < 4; ++mm) {                             \
    a[mm][0] = *(const bf16x8_t*)(Asl[BUF] + ((MOFF) + mm) * 1024 + aBase + sw0);\
    a[mm][1] = *(const bf16x8_t*)(Asl[BUF] + ((MOFF) + mm) * 1024 + aBase + sw1);\
  }
#define RD_B(BUF, N0)                                                            \
  _Pragma("unroll") for (int nn = 0; nn < 2; ++nn) {                             \
    b[(N0) + nn][0] = *(const bf16x8_t*)(Bsl[BUF] + ((N0) + nn) * 1024 + bBase + sw0); \
    b[(N0) + nn][1] = *(const bf16x8_t*)(Bsl[BUF] + ((N0) + nn) * 1024 + bBase + sw1); \
  }
#define MFMA_Q(MH, NH)                                                           \
  _Pragma("unroll") for (int mm = 0; mm < 4; ++mm)                               \
  _Pragma("unroll") for (int nn = 0; nn < 2; ++nn) {                             \
    f32x4_t& c = acc[(MH) * 4 + mm][(NH) * 2 + nn];                              \
    c = __builtin_amdgcn_mfma_f32_16x16x32_bf16(a[mm][0], b[(NH) * 2 + nn][0], c, 0, 0, 0); \
    c = __builtin_amdgcn_mfma_f32_16x16x32_bf16(a[mm][1], b[(NH) * 2 + nn][1], c, 0, 0, 0); \
  }

#define DO_ITER(T1, T2, T3, FULL)                                                \
  /* P1 */                                                                       \
  RD_A(0, 0); RD_B(0, 0);                                                        \
  STAGE(1, 0, 1, (T1));                 /* b1.A.h1 <- T1 (A free after prev P7) */\
  LGKM8();                                                                       \
  BAR8(); LGKM0();                                                               \
  __builtin_amdgcn_s_setprio(1); MFMA_Q(0, 0); __builtin_amdgcn_s_setprio(0);    \
  BAR8();                                                                        \
  /* P2 */                                                                       \
  RD_B(0, 2);                                                                    \
  BAR8(); LGKM0();                                                               \
  __builtin_amdgcn_s_setprio(1); MFMA_Q(0, 1); __builtin_amdgcn_s_setprio(0);    \
  BAR8();                                                                        \
  /* P3 */                                                                       \
  RD_A(0, 4);                                                                    \
  if (FULL) STAGE(0, 1, 0, (T2));       /* b0.B.h0 (B free after P2) */          \
  BAR8(); LGKM0();                                                               \
  __builtin_amdgcn_s_setprio(1); MFMA_Q(1, 0); __builtin_amdgcn_s_setprio(0);    \
  BAR8();                                                                        \
  /* P4 */                                                                       \
  if (FULL) { STAGE(0, 1, 1, (T2)); STAGE(0, 0, 0, (T2)); } /* b0.A free after P3 */\
  BAR8(); LGKM0();                                                               \
  __builtin_amdgcn_s_setprio(1); MFMA_Q(1, 1); __builtin_amdgcn_s_setprio(0);    \
  if (FULL) { VMC(6); } else { VMC(0); }                                         \
  BAR8();                                                                        \
  /* P5 */                                                                       \
  RD_A(1, 0); RD_B(1, 0);                                                        \
  if (FULL) STAGE(0, 0, 1, (T2));                                                \
  LGKM8();                                                                       \
  BAR8(); LGKM0();                                                               \
  __builtin_amdgcn_s_setprio(1); MFMA_Q(0, 0); __builtin_amdgcn_s_setprio(0);    \
  BAR8();                                                                        \
  /* P6 */                                                                       \
  RD_B(1, 2);                                                                    \
  BAR8(); LGKM0();                                                               \
  __builtin_amdgcn_s_setprio(1); MFMA_Q(0, 1); __builtin_amdgcn_s_setprio(0);    \
  BAR8();                                                                        \
  /* P7 */                                                                       \
  RD_A(1, 4);                                                                    \
  if (FULL) STAGE(1, 1, 0, (T3));       /* b1.B.h0 (B free after P6) */          \
  BAR8(); LGKM0();                                                               \
  __builtin_amdgcn_s_setprio(1); MFMA_Q(1, 0); __builtin_amdgcn_s_setprio(0);    \
  BAR8();                                                                        \
  /* P8 */                                                                       \
  if (FULL) { STAGE(1, 1, 1, (T3)); STAGE(1, 0, 0, (T3)); } /* b1.A free after P7 */\
  BAR8(); LGKM0();                                                               \
  __builtin_amdgcn_s_setprio(1); MFMA_Q(1, 1); __builtin_amdgcn_s_setprio(0);    \
  if (FULL) { VMC(6); }                                                          \
  BAR8();

__global__ __launch_bounds__(512, 2) void k_gemm8(
    const __bf16* __restrict__ xb, const __bf16* __restrict__ wq,
    const float* __restrict__ scale_p, float* __restrict__ out) {
  __shared__ __bf16 smem[2 * 2 * 2 * 8192];  // 128 KiB

  const int tid  = threadIdx.x;
  const int lane = tid & 63;
  const int wid  = tid >> 6;   // 0..7
  const int wr   = wid >> 2;   // M half (0..1)
  const int wc   = wid & 3;    // N quarter (0..3)
  const int lr   = lane & 15;
  const int kq   = lane >> 4;

  // XCD-chunked linear index, then 2D super-tile raster decode:
  // groups of 8 bn x 32 bm (256 tiles), bn fastest; ragged last group (bn 40-42).
  const int wg = ((int)blockIdx.x & 7) * (NWG8 / 8) + ((int)blockIdx.x >> 3);
  int bm, bn;
  if (wg < 1280) {
    const int g = wg >> 8, r = wg & 255;
    bn = g * 8 + (r & 7);
    bm = r >> 3;
  } else {
    const int r = wg - 1280;
    bn = 40 + r % 3;
    bm = r / 3;
  }

  const float scl = scale_p[0];

  // staging chunks: thread covers chunks tid and tid+512 of each half-tile
  // chunk c: row r = c>>3 (0..127), phys slot p = c&7; source slot = p ^ (r&7)
  const int c0 = tid, c1 = tid + 512;
  const int r0 = c0 >> 3, q0 = (c0 & 7) ^ (r0 & 7);
  const int r1 = c1 >> 3, q1 = (c1 & 7) ^ (r1 & 7);
  const __bf16* aPan = xb + (size_t)bm * BM8 * KD;
  const __bf16* bPan = wq + (size_t)bn * BN8 * KD;

  auto STAGE = [&](int buf, int op, int half, int tile) {
    const __bf16* pan = op ? bPan : aPan;
    const __bf16* s0 = pan + (size_t)(half * 128 + r0) * KD + tile * 64 + q0 * 8;
    const __bf16* s1 = pan + (size_t)(half * 128 + r1) * KD + tile * 64 + q1 * 8;
    __bf16* d = smem + ((buf * 2 + op) * 2 + half) * 8192;
    __builtin_amdgcn_global_load_lds((AS1 const void*)s0, (AS3 void*)(d + c0 * 8), 16, 0, 0);
    __builtin_amdgcn_global_load_lds((AS1 const void*)s1, (AS3 void*)(d + c1 * 8), 16, 0, 0);
  };

  // ds_read addressing: frag (row=R, kslot q') lives at elem R*64 + (q'^(R&7))*8.
  const int sw0 = ((kq)     ^ (lr & 7)) * 8;   // kk=0 slots 0..3
  const int sw1 = ((kq + 4) ^ (lr & 7)) * 8;   // kk=1 slots 4..7
  const int aBase = lr * 64;
  const int bBase = ((wc & 1) * 64 + lr) * 64;
  const int bhalf = wc >> 1;
  const __bf16* Asl[2] = { smem + (0 * 4 + 0 * 2 + wr) * 8192,
                           smem + (1 * 4 + 0 * 2 + wr) * 8192 };
  const __bf16* Bsl[2] = { smem + (0 * 4 + 1 * 2 + bhalf) * 8192,
                           smem + (1 * 4 + 1 * 2 + bhalf) * 8192 };

  bf16x8_t a[4][2], b[4][2];
  f32x4_t acc[8][4] = {};

  // ---- prologue: buf0 <- t0 (A+B, 8 loads), then b1.B <- t1 (4), b1.A.h0 <- t1 (2).
  // VMC(6): oldest 8 (all of buf0) landed; 6 in flight = exactly the steady-state
  // P8-end residue {b1.B.h0, b1.B.h1, b1.A.h0}. Loop's P1 stages b1.A.h1.
  STAGE(0, 0, 0, 0); STAGE(0, 0, 1, 0);
  STAGE(0, 1, 0, 0); STAGE(0, 1, 1, 0);
  STAGE(1, 1, 0, 1); STAGE(1, 1, 1, 1);
  STAGE(1, 0, 0, 1);
  VMC(6);
  BAR8();

  // ---- main loop: iterations 0..30 full, 31 peeled (no forward stages) ----
  for (int i = 0; i < 31; ++i) {
    const int t1 = 2 * i + 1, t2 = 2 * i + 2, t3 = 2 * i + 3;
    DO_ITER(t1, t2, t3, 1)
  }
  DO_ITER(63, 0, 0, 0)

  // ---- epilogue: C/D layout col=lane&15, row=(lane>>4)*4+reg ----
  // NONTEMPORAL stores: keep the 360 MB output stream out of L2/L3.
  const size_t row0 = (size_t)bm * 256 + wr * 128 + kq * 4;
  const int col0 = bn * 256 + wc * 64 + lr;
#pragma unroll
  for (int m = 0; m < 8; ++m)
#pragma unroll
    for (int j = 0; j < 4; ++j) {
      float* orow = out + (row0 + m * 16 + j) * (size_t)ND + col0;
#pragma unroll
      for (int n = 0; n < 4; ++n)
        __builtin_nontemporal_store(scl * acc[m][n][j], &orow[n * 16]);
    }
}

// ================= fallback 128^2 GEMM (round-1, fp32 on-the-fly) ================
__global__ void k_gemm_fb(const float* __restrict__ x, const float* __restrict__ w,
                          const float* __restrict__ scale_p, float* __restrict__ out) {
  __shared__ __bf16 As[BM * BK];
  __shared__ __bf16 Bs[BN * BK];

  const int tid  = threadIdx.x;
  const int lane = tid & 63;
  const int wid  = tid >> 6;
  const int wr = wid >> 1, wc = wid & 1;
  const int lr = lane & 15, kq = lane >> 4;

  int wg = ((int)blockIdx.x % 8) * (NWG / 8) + (int)blockIdx.x / 8;
  const int bm = wg % MT;
  const int bn = wg / MT;

  const float scl = scale_p[0];
  const float inv = 1.0f / scl;

  const int c0 = tid, c1 = tid + 256;
  const int r0 = c0 >> 2, kk0 = (c0 & 3) * 8;
  const int r1 = c1 >> 2, kk1 = (c1 & 3) * 8;
  const size_t aBase0 = (size_t)(bm * BM + r0) * KD;
  const size_t aBase1 = (size_t)(bm * BM + r1) * KD;
  const size_t bBase0 = (size_t)(bn * BN + r0) * KD;
  const size_t bBase1 = (size_t)(bn * BN + r1) * KD;

  f32x4_t acc[4][4] = {};

  for (int kt = 0; kt < KSTEPS; ++kt) {
    const int k0 = kt * BK;
    {
      const float* g0 = x + aBase0 + k0 + kk0;
      const float* g1 = x + aBase1 + k0 + kk1;
      f32x4_t v0 = *(const f32x4_t*)g0, v1 = *(const f32x4_t*)(g0 + 4);
      f32x4_t v2 = *(const f32x4_t*)g1, v3 = *(const f32x4_t*)(g1 + 4);
      bf16x8_t h0, h1;
#pragma unroll
      for (int j = 0; j < 4; ++j) {
        h0[j] = (__bf16)v0[j]; h0[j + 4] = (__bf16)v1[j];
        h1[j] = (__bf16)v2[j]; h1[j + 4] = (__bf16)v3[j];
      }
      *(bf16x8_t*)(&As[c0 * 8]) = h0;
      *(bf16x8_t*)(&As[c1 * 8]) = h1;
    }
    {
      const float* g0 = w + bBase0 + k0 + kk0;
      const float* g1 = w + bBase1 + k0 + kk1;
      f32x4_t v0 = *(const f32x4_t*)g0, v1 = *(const f32x4_t*)(g0 + 4);
      f32x4_t v2 = *(const f32x4_t*)g1, v3 = *(const f32x4_t*)(g1 + 4);
      bf16x8_t h0, h1;
#pragma unroll
      for (int j = 0; j < 4; ++j) {
        h0[j]     = (__bf16)fminf(1.f, fmaxf(-1.f, rintf(v0[j] * inv)));
        h0[j + 4] = (__bf16)fminf(1.f, fmaxf(-1.f, rintf(v1[j] * inv)));
        h1[j]     = (__bf16)fminf(1.f, fmaxf(-1.f, rintf(v2[j] * inv)));
        h1[j + 4] = (__bf16)fminf(1.f, fmaxf(-1.f, rintf(v3[j] * inv)));
      }
      *(bf16x8_t*)(&Bs[c0 * 8]) = h0;
      *(bf16x8_t*)(&Bs[c1 * 8]) = h1;
    }
    __syncthreads();
    bf16x8_t a[4], b[4];
#pragma unroll
    for (int m = 0; m < 4; ++m)
      a[m] = *(const bf16x8_t*)(&As[(wr * 64 + m * 16 + lr) * BK + kq * 8]);
#pragma unroll
    for (int n = 0; n < 4; ++n)
      b[n] = *(const bf16x8_t*)(&Bs[(wc * 64 + n * 16 + lr) * BK + kq * 8]);
#pragma unroll
    for (int m = 0; m < 4; ++m)
#pragma unroll
      for (int n = 0; n < 4; ++n)
        acc[m][n] = __builtin_amdgcn_mfma_f32_16x16x32_bf16(a[m], b[n], acc[m][n], 0, 0, 0);
    __syncthreads();
  }

  const size_t row0 = (size_t)bm * BM + wr * 64 + kq * 4;
  const int col0 = bn * BN + wc * 64 + lr;
#pragma unroll
  for (int m = 0; m < 4; ++m)
#pragma unroll
    for (int j = 0; j < 4; ++j) {
      float* orow = out + (row0 + m * 16 + j) * (size_t)ND + col0;
#pragma unroll
      for (int n = 0; n < 4; ++n)
        __builtin_nontemporal_store(scl * acc[m][n][j], &orow[n * 16]);
    }
}

// ---------------- launch --------------------------------------------------------
extern "C" void kernel_launch(void* const* d_in, const int* in_sizes, int n_in,
                              void* d_out, int out_size, void* d_ws, size_t ws_size,
                              hipStream_t stream) {
  (void)in_sizes; (void)n_in; (void)out_size;
  const float* x = (const float*)d_in[0];
  const float* w = (const float*)d_in[1];
  float* out = (float*)d_out;

  char* ws = (char*)d_ws;
  float*  scale_p = (float*)ws;
  double* part    = (double*)(ws + 256);
  __bf16* wq      = (__bf16*)(ws + 32768);
  __bf16* xb      = (__bf16*)(ws + 32768 + (size_t)ND * KD * 2);

  const size_t NEED_AB = 32768 + (size_t)ND * KD * 2 + (size_t)MD * KD * 2;
  const bool pre = ws_size >= NEED_AB;

  k_abs_partial<<<2048, 256, 0, stream>>>(w, part);
  k_abs_final<<<1, 256, 0, stream>>>(part, scale_p);

  if (pre) {
    k_quant_w<<<2048, 256, 0, stream>>>(w, scale_p, wq);
    k_conv_x<<<2048, 256, 0, stream>>>(x, xb);
    k_gemm8<<<NWG8, 512, 0, stream>>>(xb, wq, scale_p, out);
  } else {
    k_gemm_fb<<<NWG, 256, 0, stream>>>(x, w, scale_p, out);
  }
}

// Round 9
// 707.024 us; speedup vs baseline: 1.0407x; 1.0407x over previous
//
#include <hip/hip_runtime.h>
#include <hip/hip_bf16.h>
#include <stdint.h>

#define AS1 __attribute__((address_space(1)))
#define AS3 __attribute__((address_space(3)))

typedef __bf16 bf16x8_t __attribute__((ext_vector_type(8)));
typedef __bf16 bf16x4_t __attribute__((ext_vector_type(4)));
typedef float  f32x4_t  __attribute__((ext_vector_type(4)));

constexpr int MD = 8192;     // 4*2048 rows of x
constexpr int ND = 11008;    // weight rows = output cols
constexpr int KD = 4096;

// ---- 8-phase 256^2 kernel geometry ----
constexpr int BM8 = 256, BN8 = 256, BK8 = 64;
constexpr int MT8 = MD / BM8;      // 32
constexpr int NT8 = ND / BN8;      // 43
constexpr int NWG8 = MT8 * NT8;    // 1376 (%8==0 -> bijective XCD swizzle)

// ---- fallback 128^2 kernel geometry ----
constexpr int BM = 128, BN = 128, BK = 32;
constexpr int MT = MD / BM, NT = ND / BN, NWG = MT * NT;
constexpr int KSTEPS = KD / BK;

// ---------------- scale = mean(|W|) + eps (two-stage, deterministic, f64 acc) ----
__global__ void k_abs_partial(const float* __restrict__ w, double* __restrict__ part) {
  __shared__ double sm[256];
  const size_t n4 = (size_t)ND * KD / 4;
  const f32x4_t* w4 = (const f32x4_t*)w;
  double s = 0.0;
  for (size_t i = (size_t)blockIdx.x * 256 + threadIdx.x; i < n4; i += (size_t)gridDim.x * 256) {
    f32x4_t v = __builtin_nontemporal_load(&w4[i]);
    s += (double)fabsf(v[0]) + (double)fabsf(v[1]) + (double)fabsf(v[2]) + (double)fabsf(v[3]);
  }
  sm[threadIdx.x] = s;
  __syncthreads();
  for (int o = 128; o > 0; o >>= 1) {
    if ((int)threadIdx.x < o) sm[threadIdx.x] += sm[threadIdx.x + o];
    __syncthreads();
  }
  if (threadIdx.x == 0) part[blockIdx.x] = sm[0];
}

__global__ void k_abs_final(const double* __restrict__ part, float* __restrict__ scale_out) {
  __shared__ double sm[256];
  double s = 0.0;
  for (int i = threadIdx.x; i < 2048; i += 256) s += part[i];
  sm[threadIdx.x] = s;
  __syncthreads();
  for (int o = 128; o > 0; o >>= 1) {
    if ((int)threadIdx.x < o) sm[threadIdx.x] += sm[threadIdx.x + o];
    __syncthreads();
  }
  if (threadIdx.x == 0) {
    double mean = sm[0] / (double)((size_t)ND * KD);
    scale_out[0] = (float)mean + 1e-5f;
  }
}

// ---------------- prepass: ternary-quantize W -> bf16 {-1,0,1} -------------------
__global__ void k_quant_w(const float* __restrict__ w, const float* __restrict__ scale_p,
                          __bf16* __restrict__ wq) {
  const float s = scale_p[0];
  const size_t n4 = (size_t)ND * KD / 4;
  const f32x4_t* w4 = (const f32x4_t*)w;
  bf16x4_t* q4 = (bf16x4_t*)wq;
  for (size_t i = (size_t)blockIdx.x * 256 + threadIdx.x; i < n4; i += (size_t)gridDim.x * 256) {
    f32x4_t v = __builtin_nontemporal_load(&w4[i]);   // w is dead after this pass
    bf16x4_t h;
#pragma unroll
    for (int j = 0; j < 4; ++j) {
      float q = rintf(v[j] / s);
      q = fminf(1.f, fmaxf(-1.f, q));
      h[j] = (__bf16)q;
    }
    q4[i] = h;   // wq stays cacheable: GEMM reads it next
  }
}

// ---------------- prepass: x fp32 -> bf16 ---------------------------------------
__global__ void k_conv_x(const float* __restrict__ x, __bf16* __restrict__ xb) {
  const size_t n4 = (size_t)MD * KD / 4;
  const f32x4_t* x4 = (const f32x4_t*)x;
  bf16x4_t* o4 = (bf16x4_t*)xb;
  for (size_t i = (size_t)blockIdx.x * 256 + threadIdx.x; i < n4; i += (size_t)gridDim.x * 256) {
    f32x4_t v = __builtin_nontemporal_load(&x4[i]);   // x is dead after this pass
    bf16x4_t h;
#pragma unroll
    for (int j = 0; j < 4; ++j) h[j] = (__bf16)v[j];
    o4[i] = h;   // xb stays cacheable
  }
}

// ================= 8-phase 256x256 GEMM (m201-style template) ====================
// C[M,N] = Xb[M,K] * Wq[N,K]^T * scale. 512 thr = 8 waves (2M x 4N), each wave
// owns 128x64 output. BK=64, 2 K-tiles/iteration, 8 phases. LDS 128 KiB.
// XOR slot-swizzle applied on BOTH sides (rule #21).
//
// ROUND 9: liveness-correct ds_read software pipelining.
// Round 8's deterministic bug: a_hi issued at P1-bottom clobbered a_lo, which
// Q(0,1) at P2 still needed (quadrant order Q00,Q01,Q10,Q11 keeps a_lo live
// through P2, a_hi through P4, b_lo through P3, b_hi through P4).
// Legal overwrite points: a after Q(0,1)/Q(1,1); b after Q(1,1).
//
// ds_read issue plan (all post-MFMA at issue point, SCHB-pinned, dead regs only):
//   P4-bottom: a_lo+b_lo buf1 (12)   [a,b dead after Q11; buf1 confirmed @P3]
//   P5-bottom: b_hi buf1 (4)         [b23 dead after P4 Q11]
//   P6-bottom: a_hi buf1 (8)         [a_lo dead after P6 Q01]
//   P8-bottom: a_lo+b_lo buf0' (12)  [FULL only; buf0' confirmed @P7]
//   P1-bottom: b_hi buf0 (4)
//   P2-bottom: a_hi buf0 (8)
// MFMA operand check: P1 a_lo*b_lo | P2 a_lo*b_hi (a untouched till P2-bottom)
//   | P3 a_hi*b_lo (b_lo intact since P4'-bottom) | P4 a_hi*b_hi. Mirror P5-P8.
//
// Sync invariant (fixes round 7's race): reads of a freshly staged buffer issue
// only after a barrier that postdates EVERY wave's confirming vmcnt:
//   VMC(2)@P3-bottom: outstanding {P7',P8',P1,P2,P3}=10 -> oldest 8 = ALL buf1.
//     P3-end barrier -> P4/P5/P6-bottom reads safe.
//   VMC(2)@P7-bottom: outstanding {P3..P7}=10 -> oldest 8 = ALL buf0'.
//     P7-end barrier -> P8/P1/P2-bottom reads safe.
// Stage ring (= round-5 best):
//   P1: b1.A.h0<-T1 | P2: b1.A.h1 | P3: b0.B.h0<-T2 | P4: b0.B.h1
//   P5: b0.A.h0     | P6: b0.A.h1 | P7: b1.B.h0<-T3 | P8: b1.B.h1
// WAR audit (read-retire < re-stage, all barrier-separated):
//   buf0.B reads (P8'/P1-bottom) retired by P2 lgkm0 < P3 stage.
//   buf0.A reads (P8'/P2-bottom) retired by P3 lgkm0 < P5 stage.
//   buf1.B reads (P4/P5-bottom)  retired by P6 lgkm0 < P7 stage.
//   buf1.A reads (P4/P6-bottom)  retired by P7 lgkm0 < next-P1 stage.
// Peeled iter: VMC(0)@P3 drains all 8 outstanding (4 prev b1.B + 4 b1.A) ->
//   buf1 complete before P4-bottom reads; P8-bottom reads skipped.

#define BAR8()    __builtin_amdgcn_s_barrier()
#define LGKMC(N)  asm volatile("s_waitcnt lgkmcnt(" #N ")")
#define VMC(N)    asm volatile("s_waitcnt vmcnt(" #N ")" ::: "memory")
#define SCHB()    __builtin_amdgcn_sched_barrier(0)

#define RD_A(BUF, MOFF)                                                          \
  _Pragma("unroll") for (int mm = 0; mm < 4; ++mm) {                             \
    a[mm][0] = *(const bf16x8_t*)(Asl[BUF] + ((MOFF) + mm) * 1024 + aBase + sw0);\
    a[mm][1] = *(const bf16x8_t*)(Asl[BUF] + ((MOFF) + mm) * 1024 + aBase + sw1);\
  }
#define RD_B(BUF, N0)                                                            \
  _Pragma("unroll") for (int nn = 0; nn < 2; ++nn) {                             \
    b[(N0) + nn][0] = *(const bf16x8_t*)(Bsl[BUF] + ((N0) + nn) * 1024 + bBase + sw0); \
    b[(N0) + nn][1] = *(const bf16x8_t*)(Bsl[BUF] + ((N0) + nn) * 1024 + bBase + sw1); \
  }
#define MFMA_Q(MH, NH)                                                           \
  _Pragma("unroll") for (int mm = 0; mm < 4; ++mm)                               \
  _Pragma("unroll") for (int nn = 0; nn < 2; ++nn) {                             \
    f32x4_t& c = acc[(MH) * 4 + mm][(NH) * 2 + nn];                              \
    c = __builtin_amdgcn_mfma_f32_16x16x32_bf16(a[mm][0], b[(NH) * 2 + nn][0], c, 0, 0, 0); \
    c = __builtin_amdgcn_mfma_f32_16x16x32_bf16(a[mm][1], b[(NH) * 2 + nn][1], c, 0, 0, 0); \
  }

#define DO_ITER(T1, T2, T3, FULL)                                                \
  /* P1: Q(0,0)=a_lo*b_lo buf0 (issued prev P8-bottom) */                        \
  STAGE(1, 0, 0, (T1));                                                          \
  BAR8(); LGKMC(0);                                                              \
  __builtin_amdgcn_s_setprio(1); MFMA_Q(0, 0); __builtin_amdgcn_s_setprio(0);    \
  SCHB(); RD_B(0, 2); SCHB();              /* b_hi buf0 */                       \
  BAR8();                                                                        \
  /* P2: Q(0,1)=a_lo*b_hi */                                                     \
  STAGE(1, 0, 1, (T1));                                                          \
  BAR8(); LGKMC(0);                                                              \
  __builtin_amdgcn_s_setprio(1); MFMA_Q(0, 1); __builtin_amdgcn_s_setprio(0);    \
  SCHB(); RD_A(0, 4); SCHB();              /* a_hi buf0 (a_lo now dead) */       \
  BAR8();                                                                        \
  /* P3: Q(1,0)=a_hi*b_lo; VMC(2) confirms ALL of buf1 */                        \
  if (FULL) STAGE(0, 1, 0, (T2));                                                \
  BAR8(); LGKMC(0);                                                              \
  __builtin_amdgcn_s_setprio(1); MFMA_Q(1, 0); __builtin_amdgcn_s_setprio(0);    \
  if (FULL) { VMC(2); } else { VMC(0); }                                         \
  BAR8();                                                                        \
  /* P4: Q(1,1)=a_hi*b_hi; bottom: a_lo+b_lo buf1 (post-confirm barrier) */      \
  if (FULL) STAGE(0, 1, 1, (T2));                                                \
  BAR8();                                                                        \
  __builtin_amdgcn_s_setprio(1); MFMA_Q(1, 1); __builtin_amdgcn_s_setprio(0);    \
  SCHB(); RD_A(1, 0); RD_B(1, 0); SCHB();                                        \
  BAR8();                                                                        \
  /* P5: Q(0,0) buf1 */                                                          \
  if (FULL) STAGE(0, 0, 0, (T2));                                                \
  BAR8(); LGKMC(0);                                                              \
  __builtin_amdgcn_s_setprio(1); MFMA_Q(0, 0); __builtin_amdgcn_s_setprio(0);    \
  SCHB(); RD_B(1, 2); SCHB();              /* b_hi buf1 */                       \
  BAR8();                                                                        \
  /* P6: Q(0,1) buf1 */                                                          \
  if (FULL) STAGE(0, 0, 1, (T2));                                                \
  BAR8(); LGKMC(0);                                                              \
  __builtin_amdgcn_s_setprio(1); MFMA_Q(0, 1); __builtin_amdgcn_s_setprio(0);    \
  SCHB(); RD_A(1, 4); SCHB();              /* a_hi buf1 */                       \
  BAR8();                                                                        \
  /* P7: Q(1,0) buf1; VMC(2) confirms ALL of buf0' */                            \
  if (FULL) STAGE(1, 1, 0, (T3));                                                \
  BAR8(); LGKMC(0);                                                              \
  __builtin_amdgcn_s_setprio(1); MFMA_Q(1, 0); __builtin_amdgcn_s_setprio(0);    \
  if (FULL) { VMC(2); }                                                          \
  BAR8();                                                                        \
  /* P8: Q(1,1) buf1; bottom: a_lo+b_lo buf0' for next P1 (FULL only) */         \
  if (FULL) STAGE(1, 1, 1, (T3));                                                \
  BAR8();                                                                        \
  __builtin_amdgcn_s_setprio(1); MFMA_Q(1, 1); __builtin_amdgcn_s_setprio(0);    \
  if (FULL) { SCHB(); RD_A(0, 0); RD_B(0, 0); SCHB(); }                          \
  BAR8();

__global__ __launch_bounds__(512, 2) void k_gemm8(
    const __bf16* __restrict__ xb, const __bf16* __restrict__ wq,
    const float* __restrict__ scale_p, float* __restrict__ out) {
  __shared__ __bf16 smem[2 * 2 * 2 * 8192];  // 128 KiB

  const int tid  = threadIdx.x;
  const int lane = tid & 63;
  const int wid  = tid >> 6;   // 0..7
  const int wr   = wid >> 2;   // M half (0..1)
  const int wc   = wid & 3;    // N quarter (0..3)
  const int lr   = lane & 15;
  const int kq   = lane >> 4;

  // XCD-chunked linear index, then 2D super-tile raster decode:
  // groups of 8 bn x 32 bm (256 tiles), bn fastest; ragged last group (bn 40-42).
  const int wg = ((int)blockIdx.x & 7) * (NWG8 / 8) + ((int)blockIdx.x >> 3);
  int bm, bn;
  if (wg < 1280) {
    const int g = wg >> 8, r = wg & 255;
    bn = g * 8 + (r & 7);
    bm = r >> 3;
  } else {
    const int r = wg - 1280;
    bn = 40 + r % 3;
    bm = r / 3;
  }

  const float scl = scale_p[0];

  // staging chunks: thread covers chunks tid and tid+512 of each half-tile
  // chunk c: row r = c>>3 (0..127), phys slot p = c&7; source slot = p ^ (r&7)
  const int c0 = tid, c1 = tid + 512;
  const int r0 = c0 >> 3, q0 = (c0 & 7) ^ (r0 & 7);
  const int r1 = c1 >> 3, q1 = (c1 & 7) ^ (r1 & 7);
  const __bf16* aPan = xb + (size_t)bm * BM8 * KD;
  const __bf16* bPan = wq + (size_t)bn * BN8 * KD;

  auto STAGE = [&](int buf, int op, int half, int tile) {
    const __bf16* pan = op ? bPan : aPan;
    const __bf16* s0 = pan + (size_t)(half * 128 + r0) * KD + tile * 64 + q0 * 8;
    const __bf16* s1 = pan + (size_t)(half * 128 + r1) * KD + tile * 64 + q1 * 8;
    __bf16* d = smem + ((buf * 2 + op) * 2 + half) * 8192;
    __builtin_amdgcn_global_load_lds((AS1 const void*)s0, (AS3 void*)(d + c0 * 8), 16, 0, 0);
    __builtin_amdgcn_global_load_lds((AS1 const void*)s1, (AS3 void*)(d + c1 * 8), 16, 0, 0);
  };

  // ds_read addressing: frag (row=R, kslot q') lives at elem R*64 + (q'^(R&7))*8.
  const int sw0 = ((kq)     ^ (lr & 7)) * 8;   // kk=0 slots 0..3
  const int sw1 = ((kq + 4) ^ (lr & 7)) * 8;   // kk=1 slots 4..7
  const int aBase = lr * 64;
  const int bBase = ((wc & 1) * 64 + lr) * 64;
  const int bhalf = wc >> 1;
  const __bf16* Asl[2] = { smem + (0 * 4 + 0 * 2 + wr) * 8192,
                           smem + (1 * 4 + 0 * 2 + wr) * 8192 };
  const __bf16* Bsl[2] = { smem + (0 * 4 + 1 * 2 + bhalf) * 8192,
                           smem + (1 * 4 + 1 * 2 + bhalf) * 8192 };

  bf16x8_t a[4][2], b[4][2];
  f32x4_t acc[8][4] = {};

  // ---- prologue: buf0 <- t0 (A+B, 8 loads), b1.B <- t1 (4 loads).
  // VMC(4): oldest 8 = all of buf0 landed; barrier postdates every wave's VMC;
  // THEN issue P1's a_lo+b_lo reads. b1.A staged in P1/P2 of iter 0.
  STAGE(0, 0, 0, 0); STAGE(0, 0, 1, 0);
  STAGE(0, 1, 0, 0); STAGE(0, 1, 1, 0);
  STAGE(1, 1, 0, 1); STAGE(1, 1, 1, 1);
  VMC(4);
  BAR8();
  SCHB(); RD_A(0, 0); RD_B(0, 0); SCHB();

  // ---- main loop: iterations 0..30 full, 31 peeled (no forward stages) ----
  for (int i = 0; i < 31; ++i) {
    const int t1 = 2 * i + 1, t2 = 2 * i + 2, t3 = 2 * i + 3;
    DO_ITER(t1, t2, t3, 1)
  }
  DO_ITER(63, 0, 0, 0)

  // ---- epilogue: C/D layout col=lane&15, row=(lane>>4)*4+reg ----
  // NONTEMPORAL stores: keep the 360 MB output stream out of L2/L3.
  const size_t row0 = (size_t)bm * 256 + wr * 128 + kq * 4;
  const int col0 = bn * 256 + wc * 64 + lr;
#pragma unroll
  for (int m = 0; m < 8; ++m)
#pragma unroll
    for (int j = 0; j < 4; ++j) {
      float* orow = out + (row0 + m * 16 + j) * (size_t)ND + col0;
#pragma unroll
      for (int n = 0; n < 4; ++n)
        __builtin_nontemporal_store(scl * acc[m][n][j], &orow[n * 16]);
    }
}

// ================= fallback 128^2 GEMM (round-1, fp32 on-the-fly) ================
__global__ void k_gemm_fb(const float* __restrict__ x, const float* __restrict__ w,
                          const float* __restrict__ scale_p, float* __restrict__ out) {
  __shared__ __bf16 As[BM * BK];
  __shared__ __bf16 Bs[BN * BK];

  const int tid  = threadIdx.x;
  const int lane = tid & 63;
  const int wid  = tid >> 6;
  const int wr = wid >> 1, wc = wid & 1;
  const int lr = lane & 15, kq = lane >> 4;

  int wg = ((int)blockIdx.x % 8) * (NWG / 8) + (int)blockIdx.x / 8;
  const int bm = wg % MT;
  const int bn = wg / MT;

  const float scl = scale_p[0];
  const float inv = 1.0f / scl;

  const int c0 = tid, c1 = tid + 256;
  const int r0 = c0 >> 2, kk0 = (c0 & 3) * 8;
  const int r1 = c1 >> 2, kk1 = (c1 & 3) * 8;
  const size_t aBase0 = (size_t)(bm * BM + r0) * KD;
  const size_t aBase1 = (size_t)(bm * BM + r1) * KD;
  const size_t bBase0 = (size_t)(bn * BN + r0) * KD;
  const size_t bBase1 = (size_t)(bn * BN + r1) * KD;

  f32x4_t acc[4][4] = {};

  for (int kt = 0; kt < KSTEPS; ++kt) {
    const int k0 = kt * BK;
    {
      const float* g0 = x + aBase0 + k0 + kk0;
      const float* g1 = x + aBase1 + k0 + kk1;
      f32x4_t v0 = *(const f32x4_t*)g0, v1 = *(const f32x4_t*)(g0 + 4);
      f32x4_t v2 = *(const f32x4_t*)g1, v3 = *(const f32x4_t*)(g1 + 4);
      bf16x8_t h0, h1;
#pragma unroll
      for (int j = 0; j < 4; ++j) {
        h0[j] = (__bf16)v0[j]; h0[j + 4] = (__bf16)v1[j];
        h1[j] = (__bf16)v2[j]; h1[j + 4] = (__bf16)v3[j];
      }
      *(bf16x8_t*)(&As[c0 * 8]) = h0;
      *(bf16x8_t*)(&As[c1 * 8]) = h1;
    }
    {
      const float* g0 = w + bBase0 + k0 + kk0;
      const float* g1 = w + bBase1 + k0 + kk1;
      f32x4_t v0 = *(const f32x4_t*)g0, v1 = *(const f32x4_t*)(g0 + 4);
      f32x4_t v2 = *(const f32x4_t*)g1, v3 = *(const f32x4_t*)(g1 + 4);
      bf16x8_t h0, h1;
#pragma unroll
      for (int j = 0; j < 4; ++j) {
        h0[j]     = (__bf16)fminf(1.f, fmaxf(-1.f, rintf(v0[j] * inv)));
        h0[j + 4] = (__bf16)fminf(1.f, fmaxf(-1.f, rintf(v1[j] * inv)));
        h1[j]     = (__bf16)fminf(1.f, fmaxf(-1.f, rintf(v2[j] * inv)));
        h1[j + 4] = (__bf16)fminf(1.f, fmaxf(-1.f, rintf(v3[j] * inv)));
      }
      *(bf16x8_t*)(&Bs[c0 * 8]) = h0;
      *(bf16x8_t*)(&Bs[c1 * 8]) = h1;
    }
    __syncthreads();
    bf16x8_t a[4], b[4];
#pragma unroll
    for (int m = 0; m < 4; ++m)
      a[m] = *(const bf16x8_t*)(&As[(wr * 64 + m * 16 + lr) * BK + kq * 8]);
#pragma unroll
    for (int n = 0; n < 4; ++n)
      b[n] = *(const bf16x8_t*)(&Bs[(wc * 64 + n * 16 + lr) * BK + kq * 8]);
#pragma unroll
    for (int m = 0; m < 4; ++m)
#pragma unroll
      for (int n = 0; n < 4; ++n)
        acc[m][n] = __builtin_amdgcn_mfma_f32_16x16x32_bf16(a[m], b[n], acc[m][n], 0, 0, 0);
    __syncthreads();
  }

  const size_t row0 = (size_t)bm * BM + wr * 64 + kq * 4;
  const int col0 = bn * BN + wc * 64 + lr;
#pragma unroll
  for (int m = 0; m < 4; ++m)
#pragma unroll
    for (int j = 0; j < 4; ++j) {
      float* orow = out + (row0 + m * 16 + j) * (size_t)ND + col0;
#pragma unroll
      for (int n = 0; n < 4; ++n)
        __builtin_nontemporal_store(scl * acc[m][n][j], &orow[n * 16]);
    }
}

// ---------------- launch --------------------------------------------------------
extern "C" void kernel_launch(void* const* d_in, const int* in_sizes, int n_in,
                              void* d_out, int out_size, void* d_ws, size_t ws_size,
                              hipStream_t stream) {
  (void)in_sizes; (void)n_in; (void)out_size;
  const float* x = (const float*)d_in[0];
  const float* w = (const float*)d_in[1];
  float* out = (float*)d_out;

  char* ws = (char*)d_ws;
  float*  scale_p = (float*)ws;
  double* part    = (double*)(ws + 256);
  __bf16* wq      = (__bf16*)(ws + 32768);
  __bf16* xb      = (__bf16*)(ws + 32768 + (size_t)ND * KD * 2);

  const size_t NEED_AB = 32768 + (size_t)ND * KD * 2 + (size_t)MD * KD * 2;
  const bool pre = ws_size >= NEED_AB;

  k_abs_partial<<<2048, 256, 0, stream>>>(w, part);
  k_abs_final<<<1, 256, 0, stream>>>(part, scale_p);

  if (pre) {
    k_quant_w<<<2048, 256, 0, stream>>>(w, scale_p, wq);
    k_conv_x<<<2048, 256, 0, stream>>>(x, xb);
    k_gemm8<<<NWG8, 512, 0, stream>>>(xb, wq, scale_p, out);
  } else {
    k_gemm_fb<<<NWG, 256, 0, stream>>>(x, w, scale_p, out);
  }
}